// Round 11
// baseline (51.808 us; speedup 1.0000x reference)
//
#include <hip/hip_runtime.h>

#define BATCH   256
#define NFEAT   20000
#define NVEC    (NFEAT / 4)
#define KSEL    256
#define NSAMP   8
#define CAP     2048
#define VALID_LO 0xFFFFB1E0u   // = ~(NFEAT-1); low32 of any valid composite >= this

typedef unsigned long long u64;
typedef float __attribute__((ext_vector_type(4))) f32x4;

// Map float bits to unsigned key with same total order as float compare.
__device__ __forceinline__ unsigned fmap(float f) {
    unsigned u = __float_as_uint(f);
    return (u & 0x80000000u) ? ~u : (u | 0x80000000u);
}

// Generic top-down bin pick by wave 0 (rare refine path only).
__device__ __forceinline__ void select_bin_wave0(const unsigned* hist, int nbins, int w,
                                                 int* s_d, int* s_w, int lane) {
    for (int base = nbins - 1; base >= 0; base -= 64) {
        int bin = base - lane;
        unsigned c = (bin >= 0) ? hist[bin] : 0u;
        unsigned p = c;
#pragma unroll
        for (int off = 1; off < 64; off <<= 1) {
            unsigned t = __shfl_up(p, off);
            if (lane >= off) p += t;
        }
        unsigned long long m = __ballot(p >= (unsigned)w);
        if (m) {
            int l = __ffsll(m) - 1;
            if (lane == l) { *s_d = bin; *s_w = w - (int)(p - c); }
            return;
        }
        w -= (int)__shfl(p, 63);
    }
    if (lane == 0) { *s_d = 0; *s_w = 1; }
}

// Fast pick over exactly 64 entries (arr[63] = highest bin), wave 0 only.
__device__ __forceinline__ void pick64(const unsigned* arr, int w, int lane,
                                       int* s_idx, int* s_w) {
    unsigned c = arr[63 - lane];
    unsigned p = c;
#pragma unroll
    for (int off = 1; off < 64; off <<= 1) {
        unsigned t = __shfl_up(p, off);
        if (lane >= off) p += t;
    }
    unsigned long long m = __ballot(p >= (unsigned)w);
    if (m) {
        int l = __ffsll(m) - 1;
        if (lane == l) { *s_idx = 63 - l; *s_w = w - (int)(p - c); }
    } else if (lane == 0) { *s_idx = 0; *s_w = 1; }
}

// Specialized grid: blocks [0,256) = per-row SELECT (publish exact top-K
// threshold composite key<<32|~idx + complement checksum); blocks [256,512)
// = per-row WRITER (stream zeros for all 8 slices immediately — no
// dependency — then spin for the row threshold, then scatter the ones).
// 16+16 waves co-resident per CU => zero-streaming overlaps the select.
__global__ __launch_bounds__(1024, 8) void topk_split(const float* __restrict__ logits,
                                                      float* __restrict__ out,
                                                      u64* __restrict__ rowthr,
                                                      u64* __restrict__ rowchk) {
    const int tid = threadIdx.x;
    const size_t BN = (size_t)BATCH * NFEAT;

    __shared__ unsigned hist[4096];     // 16 KB   (select only)
    __shared__ u64 cand[CAP];           // 16 KB   (select only)
    __shared__ unsigned csum[64];
    __shared__ int s_d, s_w;
    __shared__ unsigned s_cnt;
    __shared__ u64 s_thr;
    __shared__ int s_run, s_cut, s_wc[16];

    if (blockIdx.x < BATCH) {
        // ================= SELECT block: row b =================
        const int b = blockIdx.x;
        const int lane = tid & 63, wave = tid >> 6;
        const float4* __restrict__ row4 = (const float4*)(logits + (size_t)b * NFEAT);

        // ---- Phase 1: loads + 12-bit histogram ----
        float4 v[5];
#pragma unroll
        for (int j = 0; j < 5; ++j) {
            const int i4 = tid + j * 1024;
            v[j] = row4[(i4 < NVEC) ? i4 : (NVEC - 1)];
        }
#pragma unroll
        for (int j = 0; j < 4; ++j) hist[tid + j * 1024] = 0;
        __syncthreads();

        unsigned kk[5][4];
#pragma unroll
        for (int j = 0; j < 5; ++j) {
            kk[j][0] = fmap(v[j].x); kk[j][1] = fmap(v[j].y);
            kk[j][2] = fmap(v[j].z); kk[j][3] = fmap(v[j].w);
        }
#pragma unroll
        for (int j = 0; j < 4; ++j) {
#pragma unroll
            for (int e = 0; e < 4; ++e) atomicAdd(&hist[kk[j][e] >> 20], 1u);
        }
        if (tid + 4096 < NVEC) {
#pragma unroll
            for (int e = 0; e < 4; ++e) atomicAdd(&hist[kk[4][e] >> 20], 1u);
        }
        __syncthreads();

        // ---- Phase 2: hierarchical threshold-bin pick ----
        unsigned keypref; int w;
        {
#pragma unroll
            for (int j = 0; j < 4; ++j) {
                const int cc = wave * 4 + j;
                unsigned x = hist[cc * 64 + lane];
#pragma unroll
                for (int off = 32; off; off >>= 1) x += __shfl_down(x, off);
                if (lane == 0) csum[cc] = x;
            }
            __syncthreads();
            if (wave == 0) pick64(csum, KSEL, lane, &s_d, &s_w);
            __syncthreads();
            const int chunk = s_d; const int w0 = s_w;
            if (wave == 0) pick64(&hist[chunk * 64], w0, lane, &s_d, &s_w);
            if (tid == 0) s_cnt = 0;
            __syncthreads();
            keypref = (unsigned)(chunk * 64 + s_d);
            w = s_w;
        }
        int shift = 20;

        // ---- Phase 3: gather candidate composites from registers ----
        unsigned C;
        for (;;) {
#pragma unroll
            for (int j = 0; j < 5; ++j) {
                const int i4 = tid + j * 1024;
                if (i4 < NVEC) {
#pragma unroll
                    for (int e = 0; e < 4; ++e) {
                        const unsigned k = kk[j][e];
                        if ((k >> shift) == keypref) {
                            unsigned p = atomicAdd(&s_cnt, 1u);
                            if (p < CAP) cand[p] = ((u64)k << 32) | (unsigned)~(4 * i4 + e);
                        }
                    }
                }
            }
            __syncthreads();
            C = s_cnt;
            if (C <= CAP || shift == 0) break;

            const int nb = (shift >= 12) ? 12 : shift;
            const int nsh = shift - nb;
            for (int i = tid; i < (1 << nb); i += 1024) hist[i] = 0;
            __syncthreads();
#pragma unroll
            for (int j = 0; j < 5; ++j) {
                const int i4 = tid + j * 1024;
                if (i4 < NVEC) {
#pragma unroll
                    for (int e = 0; e < 4; ++e) {
                        const unsigned k = kk[j][e];
                        if ((k >> shift) == keypref)
                            atomicAdd(&hist[(k >> nsh) & ((1u << nb) - 1u)], 1u);
                    }
                }
            }
            __syncthreads();
            if (wave == 0) select_bin_wave0(hist, 1 << nb, w, &s_d, &s_w, lane);
            if (tid == 0) s_cnt = 0;
            __syncthreads();
            keypref = (keypref << nb) | (unsigned)s_d;
            w = s_w;
            shift = nsh;
        }

        // ---- Phase 4: resolve exact threshold (12-bit radix refine) ----
        if (C <= CAP) {
            u64 pfx = keypref;
            int pshift = 32 + shift;
            bool done = false;
            while (!done) {
                const int nb = (pshift >= 12) ? 12 : pshift;
                const int nsh = pshift - nb;
                const int nbins = 1 << nb;
                for (int i = tid; i < nbins; i += 1024) hist[i] = 0;
                __syncthreads();
                for (int i = tid; i < (int)C; i += 1024) {
                    const u64 cd = cand[i];
                    if ((cd >> pshift) == pfx)
                        atomicAdd(&hist[(unsigned)(cd >> nsh) & (unsigned)(nbins - 1)], 1u);
                }
                __syncthreads();
                unsigned d;
                if (nb == 12) {
#pragma unroll
                    for (int j = 0; j < 4; ++j) {
                        const int cc = wave * 4 + j;
                        unsigned x = hist[cc * 64 + lane];
#pragma unroll
                        for (int off = 32; off; off >>= 1) x += __shfl_down(x, off);
                        if (lane == 0) csum[cc] = x;
                    }
                    __syncthreads();
                    if (wave == 0) pick64(csum, w, lane, &s_d, &s_w);
                    __syncthreads();
                    const int chunk = s_d; const int w0 = s_w;
                    if (wave == 0) pick64(&hist[chunk * 64], w0, lane, &s_d, &s_w);
                    __syncthreads();
                    d = (unsigned)(chunk * 64 + s_d);
                } else {
                    if (wave == 0) select_bin_wave0(hist, nbins, w, &s_d, &s_w, lane);
                    __syncthreads();
                    d = (unsigned)s_d;
                }
                w = s_w;
                const unsigned cnt = hist[d];
                pfx = (pfx << nb) | d;
                pshift = nsh;
                if (cnt == 1u || pshift == 0) {
                    if (cnt == 1u && pshift > 0) {
                        for (int i = tid; i < (int)C; i += 1024) {
                            const u64 cd = cand[i];
                            if ((cd >> pshift) == pfx) s_thr = cd;   // unique writer
                        }
                    } else if (tid == 0) {
                        s_thr = pfx;
                    }
                    done = true;
                }
                __syncthreads();
            }
        } else {
            // unreachable in practice: shift==0 with >CAP exact-duplicate keys.
            if (tid == 0) { s_run = 0; s_cut = 0; }
            __syncthreads();
            const int lane_ = tid & 63, wave_ = tid >> 6;
#pragma unroll 1
            for (int j = 0; j < 5; ++j) {
                const int i4 = tid + j * 1024;
                bool eq[4];
                int cnt4 = 0;
#pragma unroll
                for (int e = 0; e < 4; ++e) {
                    eq[e] = (i4 < NVEC) && (kk[j][e] == keypref);
                    cnt4 += eq[e] ? 1 : 0;
                }
                unsigned p = (unsigned)cnt4;
#pragma unroll
                for (int off = 1; off < 64; off <<= 1) {
                    unsigned t = __shfl_up(p, off);
                    if (lane_ >= off) p += t;
                }
                const unsigned excl = p - (unsigned)cnt4;
                if (lane_ == 63) s_wc[wave_] = (int)p;
                __syncthreads();
                int off0 = s_run + (int)excl;
                for (int x = 0; x < wave_; ++x) off0 += s_wc[x];
#pragma unroll
                for (int e = 0; e < 4; ++e) {
                    if (eq[e]) { if (off0 == w - 1) s_cut = 4 * i4 + e; ++off0; }
                }
                __syncthreads();
                if (tid == 0) { int t = 0; for (int x = 0; x < 16; ++x) t += s_wc[x]; s_run += t; }
                __syncthreads();
                if (s_run >= w) break;
            }
            if (tid == 0) s_thr = ((u64)keypref << 32) | (unsigned)~s_cut;
            __syncthreads();
        }

        // ---- Publish threshold + complement checksum (device scope) ----
        if (tid == 0) {
            const u64 thr = s_thr;
            __hip_atomic_store(rowthr + b, thr, __ATOMIC_RELAXED, __HIP_MEMORY_SCOPE_AGENT);
            __hip_atomic_store(rowchk + b, ~thr, __ATOMIC_RELEASE, __HIP_MEMORY_SCOPE_AGENT);
        }
    } else {
        // ================= WRITER block: row r =================
        const int r = blockIdx.x - BATCH;
        float* const outr = out + (size_t)r * NFEAT;
        const f32x4 z4 = {0.0f, 0.0f, 0.0f, 0.0f};

        // ---- zeros for all 8 slices of this row (no dependency) ----
#pragma unroll
        for (int s = 0; s < NSAMP; ++s) {
            float* const base = outr + (size_t)s * BN;
#pragma unroll
            for (int k = 0; k < 5; ++k) {
                const int pos = tid + k * 1024;
                if (pos < NVEC)
                    *reinterpret_cast<f32x4*>(base + 4 * pos) = z4;
            }
        }
        __syncthreads();   // drains vmcnt: zeros complete before ones below

        // ---- spin for this row's threshold (thread 0 polls) ----
        if (tid == 0) {
            u64 t_, c_;
            for (;;) {
                t_ = __hip_atomic_load(rowthr + r, __ATOMIC_RELAXED, __HIP_MEMORY_SCOPE_AGENT);
                c_ = __hip_atomic_load(rowchk + r, __ATOMIC_ACQUIRE, __HIP_MEMORY_SCOPE_AGENT);
                if (t_ == ~c_ && (unsigned)t_ >= VALID_LO) break;
                __builtin_amdgcn_s_sleep(32);
            }
            s_thr = t_;
        }
        __syncthreads();
        const u64 thr = s_thr;
        const unsigned thr_k = (unsigned)(thr >> 32);
        const unsigned thr_l = (unsigned)thr;

        // ---- scatter ones: ~256 positions x 8 slices ----
        const float4* __restrict__ rowl = (const float4*)(logits + (size_t)r * NFEAT);
#pragma unroll
        for (int k = 0; k < 5; ++k) {
            const int pos = tid + k * 1024;
            if (pos < NVEC) {
                const float4 v = rowl[pos];
                const int n = 4 * pos;
                const float* vf = &v.x;
#pragma unroll
                for (int e = 0; e < 4; ++e) {
                    const unsigned kx = fmap(vf[e]);
                    const bool sel = (kx > thr_k) ||
                                     (kx == thr_k && (unsigned)~(n + e) >= thr_l);
                    if (sel) {
#pragma unroll
                        for (int s = 0; s < NSAMP; ++s)
                            outr[(size_t)s * BN + n + e] = 1.0f;
                    }
                }
            }
        }
    }
}

extern "C" void kernel_launch(void* const* d_in, const int* in_sizes, int n_in,
                              void* d_out, int out_size, void* d_ws, size_t ws_size,
                              hipStream_t stream) {
    const float* logits = (const float*)d_in[0];
    float* out = (float*)d_out;
    u64* rowthr = (u64*)d_ws;            // 256 * 8 B
    u64* rowchk = rowthr + BATCH;        // 256 * 8 B (total 4 KB of d_ws)

    topk_split<<<2 * BATCH, 1024, 0, stream>>>(logits, out, rowthr, rowchk);
}